// Round 8
// baseline (187.105 us; speedup 1.0000x reference)
//
#include <hip/hip_runtime.h>
#include <hip/hip_cooperative_groups.h>
#include <math.h>

namespace cg = cooperative_groups;

// Shapes:
//   input [32,1024] f32; source_hids [2048,32,1024] f32 (256 MiB);
//   encoder_padding_mask [2048,32] bool; W_in [1024,1024]; W_out [1024,2048]
// Outputs flat: output [32,1024], beta [2048,32], alpha [2048,32]
//
// Exact simplifications (rounds 1-2):
//   alpha = p * exclusive_cumprod(1-p); beta = alpha.
//   f32: sigmoid(e)==1.0f exactly for e >~ 17.3 => (1-p)==0.0f => running
//   cumprod hits EXACT 0 => all later beta exactly 0 regardless of p.
//   => energy/scan only for s < CH=64; tails pre-zeroed; block-local exact
//   fallback (P ~ 1e-9) finishes a non-collapsed column.
//
// Round-8: ONE cooperative kernel, 3 grid.sync()s. R7 established each
// phase's work sums to ~6-9 us while total was 30.6 => ~20 us of kernel
// boundary + ramp/drain overhead. Phase shapes identical to R7's proven
// kernels; 512 blocks x 256 thr co-resident (2/CU).

#define SRC_LEN 2048
#define BSZ     32
#define DIM     1024
#define CH      64
#define TAIL4   ((SRC_LEN - CH) * BSZ / 4)   // 15872 float4 per tail array
#define NB      512

__global__ __launch_bounds__(256, 2) void k_mega(const float* __restrict__ input,
                                                 const float* __restrict__ src,
                                                 const unsigned char* __restrict__ mask,
                                                 const float* __restrict__ W_in,
                                                 const float* __restrict__ W_out,
                                                 float* __restrict__ out,
                                                 float* __restrict__ beta_out,
                                                 float* __restrict__ alpha_out,
                                                 float* __restrict__ x,
                                                 float* __restrict__ wc,
                                                 float* __restrict__ energy) {
    cg::grid_group grid = cg::this_grid();
    int bid  = blockIdx.x;
    int t    = threadIdx.x;
    int w    = t >> 6, lane = t & 63;
    int wid  = bid * 4 + w;                   // 0..2047

    __shared__ float pb[CH];
    __shared__ int   snz;
    __shared__ float cstate, crun, bcur;
    __shared__ float red[4];

    // ---- phase 1: x = input @ W_in^T (wave -> (b, 16-wide i-chunk)) + tail fill ----
    {
        int b  = wid >> 6;                    // 0..31
        int i0 = (wid & 63) * 16;             // 0..1008
        const float4* inp = (const float4*)(input + (size_t)b * DIM);
        float4 in[4];
        #pragma unroll
        for (int k = 0; k < 4; ++k) in[k] = inp[lane + 64 * k];
        #pragma unroll 4
        for (int i = 0; i < 16; ++i) {
            const float4* wr = (const float4*)(W_in + (size_t)(i0 + i) * DIM);
            float acc = 0.f;
            #pragma unroll
            for (int k = 0; k < 4; ++k) {
                float4 wv = wr[lane + 64 * k];
                acc += wv.x * in[k].x + wv.y * in[k].y + wv.z * in[k].z + wv.w * in[k].w;
            }
            #pragma unroll
            for (int off = 32; off; off >>= 1) acc += __shfl_down(acc, off);
            if (lane == 0) x[(size_t)b * DIM + i0 + i] = acc;
        }
        int i = bid * 256 + t;
        if (i < TAIL4) {
            float4 z = {0.f, 0.f, 0.f, 0.f};
            ((float4*)(beta_out  + (size_t)CH * BSZ))[i] = z;
            ((float4*)(alpha_out + (size_t)CH * BSZ))[i] = z;
        }
    }
    grid.sync();

    // ---- phase 2: energy[s,b] for s < CH (one dot per wave) ----
    {
        int s = wid >> 5, b = wid & (BSZ - 1);
        const float4* row = (const float4*)(src + ((size_t)s * BSZ + b) * DIM);
        const float4* xr  = (const float4*)(x + (size_t)b * DIM);
        float acc = 0.f;
        #pragma unroll
        for (int k = 0; k < 4; ++k) {
            float4 v = row[lane + 64 * k];
            float4 c = xr[lane + 64 * k];
            acc += v.x * c.x + v.y * c.y + v.z * c.z + v.w * c.w;
        }
        #pragma unroll
        for (int off = 32; off; off >>= 1) acc += __shfl_down(acc, off);
        if (lane == 0) energy[(size_t)s * BSZ + b] = acc;
    }
    grid.sync();

    // ---- phase 3: scan + wc (+ exact fallback), blocks 0..31 (one per b) ----
    if (bid < BSZ) {
        int b = bid;
        if (w == 0) {
            float ev = energy[(size_t)lane * BSZ + b];
            if (mask[(size_t)lane * BSZ + b]) ev = -1e9f;
            float p  = 1.0f / (1.0f + expf(-ev));
            float om = 1.0f - p;
            float prod = om;
            #pragma unroll
            for (int off = 1; off < 64; off <<= 1) {
                float o = __shfl_up(prod, off);
                if (lane >= off) prod *= o;
            }
            float excl = __shfl_up(prod, 1);
            if (lane == 0) excl = 1.0f;
            float a = p * excl;
            beta_out[(size_t)lane * BSZ + b]  = a;
            alpha_out[(size_t)lane * BSZ + b] = a;
            pb[lane] = a;
            unsigned long long nz = __ballot(a != 0.0f);
            if (lane == 0) snz = (nz == 0ULL) ? 0 : (64 - __builtin_clzll(nz));
            if (lane == 63) cstate = prod;
        }
        __syncthreads();

        // weighted context over the nonzero prefix; thread t owns float4 t of row b
        float4 acc = {0.f, 0.f, 0.f, 0.f};
        int smax = snz;
        for (int s = 0; s < smax; ++s) {
            float wgt = pb[s];
            if (wgt != 0.0f) {
                float4 v = ((const float4*)(src + ((size_t)s * BSZ + b) * DIM))[t];
                acc.x += wgt * v.x; acc.y += wgt * v.y;
                acc.z += wgt * v.z; acc.w += wgt * v.w;
            }
        }

        // sequential fallback for a non-collapsed column (exact; ~never runs)
        if (cstate != 0.0f) {
            float4 xv = ((const float4*)(x + (size_t)b * DIM))[t];
            if (t == 0) crun = cstate;
            __syncthreads();
            for (int s = CH; s < SRC_LEN; ++s) {
                float4 v = ((const float4*)(src + ((size_t)s * BSZ + b) * DIM))[t];
                float part = v.x * xv.x + v.y * xv.y + v.z * xv.z + v.w * xv.w;
                #pragma unroll
                for (int off = 32; off; off >>= 1) part += __shfl_down(part, off);
                if (lane == 0) red[w] = part;
                __syncthreads();
                if (t == 0) {
                    float ev = red[0] + red[1] + red[2] + red[3];
                    if (mask[(size_t)s * BSZ + b]) ev = -1e9f;
                    float p = 1.0f / (1.0f + expf(-ev));
                    float a = p * crun;
                    beta_out[(size_t)s * BSZ + b]  = a;
                    alpha_out[(size_t)s * BSZ + b] = a;
                    bcur = a;
                    crun = crun * (1.0f - p);
                }
                __syncthreads();
                float bb = bcur;
                acc.x += bb * v.x; acc.y += bb * v.y;
                acc.z += bb * v.z; acc.w += bb * v.w;
                if (crun == 0.0f) break;
            }
        }
        ((float4*)(wc + (size_t)b * DIM))[t] = acc;
    }
    grid.sync();

    // ---- phase 4: out = tanh([wc, input] @ W_out^T) (wave -> (b, 16-wide o-chunk)) ----
    {
        int b  = wid >> 6;                    // 0..31
        int o0 = (wid & 63) * 16;             // 0..1008
        const float4* wcp = (const float4*)(wc    + (size_t)b * DIM);
        const float4* inp = (const float4*)(input + (size_t)b * DIM);
        float4 c[4], u[4];
        #pragma unroll
        for (int k = 0; k < 4; ++k) {
            c[k] = wcp[lane + 64 * k];
            u[k] = inp[lane + 64 * k];
        }
        #pragma unroll 4
        for (int i = 0; i < 16; ++i) {
            const float4* wr = (const float4*)(W_out + (size_t)(o0 + i) * 2 * DIM);
            float acc = 0.f;
            #pragma unroll
            for (int k = 0; k < 4; ++k) {
                float4 wv = wr[lane + 64 * k];            // pairs with wc part
                acc += wv.x * c[k].x + wv.y * c[k].y + wv.z * c[k].z + wv.w * c[k].w;
            }
            #pragma unroll
            for (int k = 0; k < 4; ++k) {
                float4 wv = wr[256 + lane + 64 * k];      // pairs with input part
                acc += wv.x * u[k].x + wv.y * u[k].y + wv.z * u[k].z + wv.w * u[k].w;
            }
            #pragma unroll
            for (int off = 32; off; off >>= 1) acc += __shfl_down(acc, off);
            if (lane == 0) out[(size_t)b * DIM + o0 + i] = tanhf(acc);
        }
    }
}

extern "C" void kernel_launch(void* const* d_in, const int* in_sizes, int n_in,
                              void* d_out, int out_size, void* d_ws, size_t ws_size,
                              hipStream_t stream) {
    const float* input = (const float*)d_in[0];
    const float* src   = (const float*)d_in[1];
    const unsigned char* mask = (const unsigned char*)d_in[2];
    const float* W_in  = (const float*)d_in[3];
    const float* W_out = (const float*)d_in[4];

    float* out_proj  = (float*)d_out;                 // [32,1024]
    float* beta_out  = out_proj + BSZ * DIM;          // [2048,32]
    float* alpha_out = beta_out + SRC_LEN * BSZ;      // [2048,32]

    float* ws = (float*)d_ws;
    float* x      = ws;                    // 32768 floats
    float* wc     = x + BSZ * DIM;         // 32768 floats
    float* energy = wc + BSZ * DIM;        // 2048 floats

    void* kargs[] = {
        (void*)&input, (void*)&src, (void*)&mask, (void*)&W_in, (void*)&W_out,
        (void*)&out_proj, (void*)&beta_out, (void*)&alpha_out,
        (void*)&x, (void*)&wc, (void*)&energy
    };
    hipLaunchCooperativeKernel((void*)k_mega, dim3(NB), dim3(256), kargs, 0, stream);
}

// Round 9
// 32.963 us; speedup vs baseline: 5.6763x; 5.6763x over previous
//
#include <hip/hip_runtime.h>
#include <hip/hip_bf16.h>
#include <math.h>

// Shapes:
//   input [32,1024] f32; source_hids [2048,32,1024] f32 (256 MiB);
//   encoder_padding_mask [2048,32] bool; W_in [1024,1024]; W_out [1024,2048]
// Outputs flat: output [32,1024], beta [2048,32], alpha [2048,32]
//
// Exact simplifications (rounds 1-2):
//   alpha = p * exclusive_cumprod(1-p); beta = alpha.
//   f32: sigmoid(e)==1.0f exactly for e >~ 17.3 => (1-p)==0.0f => running
//   cumprod hits EXACT 0 => all later beta exactly 0 regardless of p.
//   => energy/scan only for s < CH=64; tails pre-zeroed; exact sequential
//   fallback (P ~ 1e-9) finishes a non-collapsed column.
//
// Round-9: revert from grid.sync (R8: 184us, VALUBusy 2.9% — the software
// grid barrier spins ~50us across 8 non-coherent XCDs; a kernel boundary is
// ~2us, 25x cheaper). Back to R7's proven shapes, with:
//   (a) out = tanh(wc@W1^T + input@W2^T): the input-half GEMV moves into
//       kernel 1 (independent of xproj) => critical-path k_out halves;
//   (b) energy fused into scan_wc (R3/R4: fused==split) => one less boundary.
// 3 kernels total.

#define SRC_LEN 2048
#define BSZ     32
#define DIM     1024
#define CH      64
#define TAIL4   ((SRC_LEN - CH) * BSZ / 4)   // 15872 float4 per tail array
#define XPB     512                          // xproj blocks (2048 waves)
#define OPB     512                          // out-input-half blocks (2048 waves)
#define FILLB   (TAIL4 / 256)                // 62 tail-fill blocks
#define NB1     (XPB + OPB + FILLB)

// ---------------- kernel 1: xproj + out-input-half + tail fill ----------------
__global__ __launch_bounds__(256) void k_front(const float* __restrict__ input,
                                               const float* __restrict__ W_in,
                                               const float* __restrict__ W_out,
                                               float* __restrict__ x,
                                               float* __restrict__ outacc,
                                               float* __restrict__ beta_out,
                                               float* __restrict__ alpha_out) {
    int bid = blockIdx.x;
    int t = threadIdx.x;
    int lane = t & 63;
    if (bid < XPB) {
        // x = input @ W_in^T ; wave -> (b, 16-wide i-chunk)
        int wid = bid * 4 + (t >> 6);             // 0..2047
        int b   = wid >> 6;                       // 0..31
        int i0  = (wid & 63) * 16;                // 0..1008
        const float4* inp = (const float4*)(input + (size_t)b * DIM);
        float4 in[4];
        #pragma unroll
        for (int k = 0; k < 4; ++k) in[k] = inp[lane + 64 * k];
        #pragma unroll 4
        for (int i = 0; i < 16; ++i) {
            const float4* wr = (const float4*)(W_in + (size_t)(i0 + i) * DIM);
            float acc = 0.f;
            #pragma unroll
            for (int k = 0; k < 4; ++k) {
                float4 wv = wr[lane + 64 * k];
                acc += wv.x * in[k].x + wv.y * in[k].y + wv.z * in[k].z + wv.w * in[k].w;
            }
            #pragma unroll
            for (int off = 32; off; off >>= 1) acc += __shfl_down(acc, off);
            if (lane == 0) x[(size_t)b * DIM + i0 + i] = acc;
        }
    } else if (bid < XPB + OPB) {
        // outacc = input @ W_out[:, DIM:]^T ; wave -> (b, 16-wide o-chunk)
        int wid = (bid - XPB) * 4 + (t >> 6);     // 0..2047
        int b   = wid >> 6;                       // 0..31
        int o0  = (wid & 63) * 16;                // 0..1008
        const float4* inp = (const float4*)(input + (size_t)b * DIM);
        float4 u[4];
        #pragma unroll
        for (int k = 0; k < 4; ++k) u[k] = inp[lane + 64 * k];
        #pragma unroll 4
        for (int i = 0; i < 16; ++i) {
            const float4* wr = (const float4*)(W_out + (size_t)(o0 + i) * 2 * DIM + DIM);
            float acc = 0.f;
            #pragma unroll
            for (int k = 0; k < 4; ++k) {
                float4 wv = wr[lane + 64 * k];
                acc += wv.x * u[k].x + wv.y * u[k].y + wv.z * u[k].z + wv.w * u[k].w;
            }
            #pragma unroll
            for (int off = 32; off; off >>= 1) acc += __shfl_down(acc, off);
            if (lane == 0) outacc[(size_t)b * DIM + o0 + i] = acc;
        }
    } else {
        // coalesced float4 zero-fill of beta/alpha tails
        int i = (bid - XPB - OPB) * 256 + t;      // < TAIL4 by construction
        float4 z = {0.f, 0.f, 0.f, 0.f};
        ((float4*)(beta_out  + (size_t)CH * BSZ))[i] = z;
        ((float4*)(alpha_out + (size_t)CH * BSZ))[i] = z;
    }
}

// ---------------- kernel 2: fused energy(s<CH) + scan + wc (+ exact fallback) ----------------
// 32 blocks (one per b) x 1024 threads; all reads L2/L3-hot.
__global__ __launch_bounds__(1024) void k_attn(const float* __restrict__ src,
                                               const float* __restrict__ x,
                                               const unsigned char* __restrict__ mask,
                                               float* __restrict__ beta_out,
                                               float* __restrict__ alpha_out,
                                               float* __restrict__ wc) {
    int b = blockIdx.x;
    int t = threadIdx.x;
    int w = t >> 6, lane = t & 63;
    __shared__ float e[CH];
    __shared__ float pb[CH];
    __shared__ int   snz;
    __shared__ float cstate, crun, bcur;
    __shared__ float red[16];

    // energies: wave w owns rows {w, w+16, w+32, w+48}; x read from global (L2-hot)
    const float4* xr = (const float4*)(x + (size_t)b * DIM);
    #pragma unroll
    for (int r = 0; r < 4; ++r) {
        int s = w + 16 * r;
        const float4* row = (const float4*)(src + ((size_t)s * BSZ + b) * DIM);
        float acc = 0.f;
        #pragma unroll
        for (int it = 0; it < 4; ++it) {
            float4 v = row[it * 64 + lane];
            float4 c = xr[it * 64 + lane];
            acc += v.x * c.x + v.y * c.y + v.z * c.z + v.w * c.w;
        }
        #pragma unroll
        for (int off = 32; off; off >>= 1) acc += __shfl_down(acc, off);
        if (lane == 0) e[s] = acc;
    }
    __syncthreads();

    // wave 0: sigmoid + exclusive cumprod scan
    if (w == 0) {
        float ev = e[lane];
        if (mask[(size_t)lane * BSZ + b]) ev = -1e9f;
        float p  = 1.0f / (1.0f + expf(-ev));
        float om = 1.0f - p;
        float prod = om;
        #pragma unroll
        for (int off = 1; off < 64; off <<= 1) {
            float o = __shfl_up(prod, off);
            if (lane >= off) prod *= o;
        }
        float excl = __shfl_up(prod, 1);
        if (lane == 0) excl = 1.0f;
        float a = p * excl;
        beta_out[(size_t)lane * BSZ + b]  = a;
        alpha_out[(size_t)lane * BSZ + b] = a;
        pb[lane] = a;
        unsigned long long nz = __ballot(a != 0.0f);
        if (lane == 0) snz = (nz == 0ULL) ? 0 : (64 - __builtin_clzll(nz));
        if (lane == 63) cstate = prod;
    }
    __syncthreads();

    // weighted context over the nonzero prefix; thread t owns wc[b, t]
    float acc = 0.f;
    int smax = snz;
    for (int s = 0; s < smax; ++s) {
        float wgt = pb[s];
        if (wgt != 0.0f) acc += wgt * src[((size_t)s * BSZ + b) * DIM + t];
    }

    // sequential fallback for a non-collapsed column (exact; ~never runs)
    if (cstate != 0.0f) {
        if (t == 0) crun = cstate;
        __syncthreads();
        for (int s = CH; s < SRC_LEN; ++s) {
            float v = src[((size_t)s * BSZ + b) * DIM + t];
            float part = v * x[(size_t)b * DIM + t];
            #pragma unroll
            for (int off = 32; off; off >>= 1) part += __shfl_down(part, off);
            if (lane == 0) red[w] = part;
            __syncthreads();
            if (t == 0) {
                float ev = 0.f;
                #pragma unroll
                for (int i = 0; i < 16; ++i) ev += red[i];
                if (mask[(size_t)s * BSZ + b]) ev = -1e9f;
                float p = 1.0f / (1.0f + expf(-ev));
                float a = p * crun;
                beta_out[(size_t)s * BSZ + b]  = a;
                alpha_out[(size_t)s * BSZ + b] = a;
                bcur = a;
                crun = crun * (1.0f - p);
            }
            __syncthreads();
            acc += bcur * v;
            if (crun == 0.0f) break;
        }
    }

    wc[(size_t)b * DIM + t] = acc;
}

// ---------------- kernel 3: out = tanh(wc @ W_out[:, :DIM]^T + outacc) ----------------
// 512 blocks x 256 thr = 2048 waves; wave -> (b, 16-wide o-chunk)
__global__ __launch_bounds__(256) void k_out(const float* __restrict__ wc,
                                             const float* __restrict__ outacc,
                                             const float* __restrict__ W,
                                             float* __restrict__ out) {
    int wid  = blockIdx.x * 4 + (threadIdx.x >> 6);   // 0..2047
    int lane = threadIdx.x & 63;
    int b    = wid >> 6;                              // 0..31
    int o0   = (wid & 63) * 16;                       // 0..1008
    const float4* wcp = (const float4*)(wc + (size_t)b * DIM);
    float4 c[4];
    #pragma unroll
    for (int k = 0; k < 4; ++k) c[k] = wcp[lane + 64 * k];
    #pragma unroll 4
    for (int i = 0; i < 16; ++i) {
        const float4* wr = (const float4*)(W + (size_t)(o0 + i) * 2 * DIM);
        float acc = 0.f;
        #pragma unroll
        for (int k = 0; k < 4; ++k) {
            float4 wv = wr[lane + 64 * k];
            acc += wv.x * c[k].x + wv.y * c[k].y + wv.z * c[k].z + wv.w * c[k].w;
        }
        #pragma unroll
        for (int off = 32; off; off >>= 1) acc += __shfl_down(acc, off);
        if (lane == 0)
            out[(size_t)b * DIM + o0 + i] = tanhf(acc + outacc[(size_t)b * DIM + o0 + i]);
    }
}

extern "C" void kernel_launch(void* const* d_in, const int* in_sizes, int n_in,
                              void* d_out, int out_size, void* d_ws, size_t ws_size,
                              hipStream_t stream) {
    const float* input = (const float*)d_in[0];
    const float* src   = (const float*)d_in[1];
    const unsigned char* mask = (const unsigned char*)d_in[2];
    const float* W_in  = (const float*)d_in[3];
    const float* W_out = (const float*)d_in[4];

    float* out_proj  = (float*)d_out;                 // [32,1024]
    float* beta_out  = out_proj + BSZ * DIM;          // [2048,32]
    float* alpha_out = beta_out + SRC_LEN * BSZ;      // [2048,32]

    float* ws = (float*)d_ws;
    float* x      = ws;                    // 32768 floats
    float* wc     = x + BSZ * DIM;         // 32768 floats
    float* outacc = wc + BSZ * DIM;        // 32768 floats

    k_front<<<NB1, 256, 0, stream>>>(input, W_in, W_out, x, outacc, beta_out, alpha_out);
    k_attn<<<BSZ, 1024, 0, stream>>>(src, x, mask, beta_out, alpha_out, wc);
    k_out<<<512, 256, 0, stream>>>(wc, outacc, W_out, out_proj);
}

// Round 10
// 31.847 us; speedup vs baseline: 5.8750x; 1.0350x over previous
//
#include <hip/hip_runtime.h>
#include <hip/hip_bf16.h>
#include <math.h>

// Shapes:
//   input [32,1024] f32; source_hids [2048,32,1024] f32 (256 MiB);
//   encoder_padding_mask [2048,32] bool; W_in [1024,1024]; W_out [1024,2048]
// Outputs flat: output [32,1024], beta [2048,32], alpha [2048,32]
//
// Exact simplifications (rounds 1-2):
//   alpha = p * exclusive_cumprod(1-p); beta = alpha.
//   f32: sigmoid(e)==1.0f exactly for e >~ 17.3 => (1-p)==0.0f => running
//   cumprod hits EXACT 0 => all later beta exactly 0 regardless of p.
//   => energy/scan only for s < CH=64; tails pre-zeroed; exact sequential
//   fallback (P ~ 1e-9) finishes a non-collapsed column.
//
// Round-10 = R7 (proven 30.6us) + R9's good half only:
//   - K1: xproj + outacc(= input @ W_out[:,DIM:]^T) + tail fill (all
//     independent, 1086 small blocks -> all CUs busy)
//   - K2: energy WIDE (2048 waves; R9 proved narrow energy costs ~4us > 2us
//     boundary saved)
//   - K3: scan + wc (32 blocks; cache-hot)
//   - K4: out = tanh(wc @ W_out[:,:DIM]^T + outacc)  (half of R7's k_out)
// Governing law (R6/R8/R9): every phase is latency-bound; time ~ 1/waves.
// Keep all weight-streaming GEMVs wide across all CUs.

#define SRC_LEN 2048
#define BSZ     32
#define DIM     1024
#define CH      64
#define TAIL4   ((SRC_LEN - CH) * BSZ / 4)   // 15872 float4 per tail array
#define XPB     512                          // xproj blocks (2048 waves)
#define OPB     512                          // outacc blocks (2048 waves)
#define FILLB   (TAIL4 / 256)                // 62 tail-fill blocks
#define NB1     (XPB + OPB + FILLB)

// ---------------- kernel 1: xproj + outacc + tail fill ----------------
__global__ __launch_bounds__(256) void k_front(const float* __restrict__ input,
                                               const float* __restrict__ W_in,
                                               const float* __restrict__ W_out,
                                               float* __restrict__ x,
                                               float* __restrict__ outacc,
                                               float* __restrict__ beta_out,
                                               float* __restrict__ alpha_out) {
    int bid = blockIdx.x;
    int t = threadIdx.x;
    int lane = t & 63;
    if (bid < XPB) {
        // x = input @ W_in^T ; wave -> (b, 16-wide i-chunk)
        int wid = bid * 4 + (t >> 6);             // 0..2047
        int b   = wid >> 6;                       // 0..31
        int i0  = (wid & 63) * 16;                // 0..1008
        const float4* inp = (const float4*)(input + (size_t)b * DIM);
        float4 in[4];
        #pragma unroll
        for (int k = 0; k < 4; ++k) in[k] = inp[lane + 64 * k];
        #pragma unroll 4
        for (int i = 0; i < 16; ++i) {
            const float4* wr = (const float4*)(W_in + (size_t)(i0 + i) * DIM);
            float acc = 0.f;
            #pragma unroll
            for (int k = 0; k < 4; ++k) {
                float4 wv = wr[lane + 64 * k];
                acc += wv.x * in[k].x + wv.y * in[k].y + wv.z * in[k].z + wv.w * in[k].w;
            }
            #pragma unroll
            for (int off = 32; off; off >>= 1) acc += __shfl_down(acc, off);
            if (lane == 0) x[(size_t)b * DIM + i0 + i] = acc;
        }
    } else if (bid < XPB + OPB) {
        // outacc = input @ W_out[:, DIM:]^T ; wave -> (b, 16-wide o-chunk)
        int wid = (bid - XPB) * 4 + (t >> 6);     // 0..2047
        int b   = wid >> 6;                       // 0..31
        int o0  = (wid & 63) * 16;                // 0..1008
        const float4* inp = (const float4*)(input + (size_t)b * DIM);
        float4 u[4];
        #pragma unroll
        for (int k = 0; k < 4; ++k) u[k] = inp[lane + 64 * k];
        #pragma unroll 4
        for (int i = 0; i < 16; ++i) {
            const float4* wr = (const float4*)(W_out + (size_t)(o0 + i) * 2 * DIM + DIM);
            float acc = 0.f;
            #pragma unroll
            for (int k = 0; k < 4; ++k) {
                float4 wv = wr[lane + 64 * k];
                acc += wv.x * u[k].x + wv.y * u[k].y + wv.z * u[k].z + wv.w * u[k].w;
            }
            #pragma unroll
            for (int off = 32; off; off >>= 1) acc += __shfl_down(acc, off);
            if (lane == 0) outacc[(size_t)b * DIM + o0 + i] = acc;
        }
    } else {
        // coalesced float4 zero-fill of beta/alpha tails
        int i = (bid - XPB - OPB) * 256 + t;      // < TAIL4 by construction
        float4 z = {0.f, 0.f, 0.f, 0.f};
        ((float4*)(beta_out  + (size_t)CH * BSZ))[i] = z;
        ((float4*)(alpha_out + (size_t)CH * BSZ))[i] = z;
    }
}

// ---------------- kernel 2: energies (s<CH), wide: one (s,b) dot per wave ----------------
__global__ __launch_bounds__(256) void k_energy(const float* __restrict__ src,
                                                const float* __restrict__ x,
                                                float* __restrict__ energy) {
    int wid  = blockIdx.x * 4 + (threadIdx.x >> 6);   // 0..2047
    int lane = threadIdx.x & 63;
    int s = wid >> 5, b = wid & (BSZ - 1);
    const float4* row = (const float4*)(src + ((size_t)s * BSZ + b) * DIM);
    const float4* xr  = (const float4*)(x + (size_t)b * DIM);
    float acc = 0.f;
    #pragma unroll
    for (int k = 0; k < 4; ++k) {
        float4 v = row[lane + 64 * k];
        float4 c = xr[lane + 64 * k];
        acc += v.x * c.x + v.y * c.y + v.z * c.z + v.w * c.w;
    }
    #pragma unroll
    for (int off = 32; off; off >>= 1) acc += __shfl_down(acc, off);
    if (lane == 0) energy[(size_t)s * BSZ + b] = acc;
}

// ---------------- kernel 3: scan + wc (+ exact sequential fallback) ----------------
// 32 blocks (one per b), 1024 threads; reads are L2/L3-hot.
__global__ __launch_bounds__(1024) void k_scan_wc(const float* __restrict__ src,
                                                  const float* __restrict__ x,
                                                  const unsigned char* __restrict__ mask,
                                                  const float* __restrict__ energy,
                                                  float* __restrict__ beta_out,
                                                  float* __restrict__ alpha_out,
                                                  float* __restrict__ wc) {
    int b = blockIdx.x;
    int t = threadIdx.x;
    int w = t >> 6, lane = t & 63;
    __shared__ float pb[CH];
    __shared__ int   snz;      // number of leading rows with beta != 0
    __shared__ float cstate;
    __shared__ float red[16];
    __shared__ float crun, bcur;
    __shared__ __align__(16) float xs[DIM];

    // wave 0: sigmoid + exclusive cumprod scan over s < CH
    if (w == 0) {
        float ev = energy[(size_t)lane * BSZ + b];
        if (mask[(size_t)lane * BSZ + b]) ev = -1e9f;
        float p  = 1.0f / (1.0f + expf(-ev));
        float om = 1.0f - p;
        float prod = om;
        #pragma unroll
        for (int off = 1; off < 64; off <<= 1) {
            float o = __shfl_up(prod, off);
            if (lane >= off) prod *= o;
        }
        float excl = __shfl_up(prod, 1);
        if (lane == 0) excl = 1.0f;
        float a = p * excl;
        beta_out[(size_t)lane * BSZ + b]  = a;
        alpha_out[(size_t)lane * BSZ + b] = a;
        pb[lane] = a;
        unsigned long long nz = __ballot(a != 0.0f);
        if (lane == 0) snz = (nz == 0ULL) ? 0 : (64 - __builtin_clzll(nz));
        if (lane == 63) cstate = prod;
    }
    __syncthreads();

    // weighted context over the nonzero prefix (rows cache-hot)
    float acc = 0.f;                       // thread t owns wc[b, t]
    int smax = snz;
    for (int s = 0; s < smax; ++s) {
        float wgt = pb[s];
        if (wgt != 0.0f) acc += wgt * src[((size_t)s * BSZ + b) * DIM + t];
    }

    // sequential fallback for a non-collapsed column (exact; ~never runs)
    if (cstate != 0.0f) {
        for (int i = t; i < DIM; i += 1024) xs[i] = x[(size_t)b * DIM + i];
        if (t == 0) crun = cstate;
        __syncthreads();
        for (int s = CH; s < SRC_LEN; ++s) {
            float v = src[((size_t)s * BSZ + b) * DIM + t];
            float part = v * xs[t];
            #pragma unroll
            for (int off = 32; off; off >>= 1) part += __shfl_down(part, off);
            if (lane == 0) red[w] = part;
            __syncthreads();
            if (t == 0) {
                float ev = 0.f;
                #pragma unroll
                for (int i = 0; i < 16; ++i) ev += red[i];
                if (mask[(size_t)s * BSZ + b]) ev = -1e9f;
                float p = 1.0f / (1.0f + expf(-ev));
                float a = p * crun;
                beta_out[(size_t)s * BSZ + b]  = a;
                alpha_out[(size_t)s * BSZ + b] = a;
                bcur = a;
                crun = crun * (1.0f - p);
            }
            __syncthreads();
            acc += bcur * v;
            if (crun == 0.0f) break;
        }
    }

    wc[(size_t)b * DIM + t] = acc;
}

// ---------------- kernel 4: out = tanh(wc @ W_out[:, :DIM]^T + outacc) ----------------
// 512 blocks x 256 thr = 2048 waves; wave -> (b, 16-wide o-chunk)
__global__ __launch_bounds__(256) void k_out(const float* __restrict__ wc,
                                             const float* __restrict__ outacc,
                                             const float* __restrict__ W,
                                             float* __restrict__ out) {
    int wid  = blockIdx.x * 4 + (threadIdx.x >> 6);   // 0..2047
    int lane = threadIdx.x & 63;
    int b    = wid >> 6;                              // 0..31
    int o0   = (wid & 63) * 16;                       // 0..1008
    const float4* wcp = (const float4*)(wc + (size_t)b * DIM);
    float4 c[4];
    #pragma unroll
    for (int k = 0; k < 4; ++k) c[k] = wcp[lane + 64 * k];
    #pragma unroll 4
    for (int i = 0; i < 16; ++i) {
        const float4* wr = (const float4*)(W + (size_t)(o0 + i) * 2 * DIM);
        float acc = 0.f;
        #pragma unroll
        for (int k = 0; k < 4; ++k) {
            float4 wv = wr[lane + 64 * k];
            acc += wv.x * c[k].x + wv.y * c[k].y + wv.z * c[k].z + wv.w * c[k].w;
        }
        #pragma unroll
        for (int off = 32; off; off >>= 1) acc += __shfl_down(acc, off);
        if (lane == 0)
            out[(size_t)b * DIM + o0 + i] = tanhf(acc + outacc[(size_t)b * DIM + o0 + i]);
    }
}

extern "C" void kernel_launch(void* const* d_in, const int* in_sizes, int n_in,
                              void* d_out, int out_size, void* d_ws, size_t ws_size,
                              hipStream_t stream) {
    const float* input = (const float*)d_in[0];
    const float* src   = (const float*)d_in[1];
    const unsigned char* mask = (const unsigned char*)d_in[2];
    const float* W_in  = (const float*)d_in[3];
    const float* W_out = (const float*)d_in[4];

    float* out_proj  = (float*)d_out;                 // [32,1024]
    float* beta_out  = out_proj + BSZ * DIM;          // [2048,32]
    float* alpha_out = beta_out + SRC_LEN * BSZ;      // [2048,32]

    float* ws = (float*)d_ws;
    float* x      = ws;                    // 32768 floats
    float* wc     = x + BSZ * DIM;         // 32768 floats
    float* outacc = wc + BSZ * DIM;        // 32768 floats
    float* energy = outacc + BSZ * DIM;    // 2048 floats

    k_front<<<NB1, 256, 0, stream>>>(input, W_in, W_out, x, outacc, beta_out, alpha_out);
    k_energy<<<512, 256, 0, stream>>>(src, x, energy);
    k_scan_wc<<<BSZ, 1024, 0, stream>>>(src, x, mask, energy, beta_out, alpha_out, wc);
    k_out<<<512, 256, 0, stream>>>(wc, outacc, W_out, out_proj);
}